// Round 7
// baseline (1313.764 us; speedup 1.0000x reference)
//
#include <hip/hip_runtime.h>
#include <hip/hip_bf16.h>

// GRU scan with sparse resets. T=1024, B=256, D=128, H=128.
// Round 7: 16-batch MFMA scan. Phase 1: gi = seq @ Wi (f16 -> d_ws, ~75us).
// Phase 2: 16 blocks x 256 thr (4 waves, 1/SIMD). Per step, one block does
// h(16x128) @ Wh(128x384) as 24 mfma_f32_16x16x32_f16 per wave? no: 6 per
// wave x 4 k-chunks = 24 MFMA/wave, wave w owns hidden cols [w*32,w*32+32)
// across all 3 gates -> r,z,n of a column land in the SAME lane. r/z accs
// init = gi fragments (2-step register prefetch from ws); n acc separate
// (r multiplies only the h-part). h tile f16 in LDS, XOR-swizzled; BARL
// (lgkmcnt-only) barrier; ys stores fire-and-forget; resets as bitmasks.

#define T_STEPS 1024
#define B_SZ 256
#define D_SZ 128
#define H_SZ 128
#define BPB 16
#define NSCAN_THR 256

typedef _Float16 h2 __attribute__((ext_vector_type(2)));
typedef _Float16 h8 __attribute__((ext_vector_type(8)));
typedef _Float16 f16x8 __attribute__((ext_vector_type(8)));
typedef _Float16 f16x4 __attribute__((ext_vector_type(4)));
typedef float f32x4 __attribute__((ext_vector_type(4)));

union U8 { h8 v; h2 p[4]; };

__device__ __forceinline__ float dot2f(h2 a, h2 b, float c) {
#if __has_builtin(__builtin_amdgcn_fdot2)
  return __builtin_amdgcn_fdot2(a, b, c, false);
#else
  return c + (float)a.x * (float)b.x + (float)a.y * (float)b.y;
#endif
}

__device__ __forceinline__ float fastrcp(float x) {
#if __has_builtin(__builtin_amdgcn_rcpf)
  return __builtin_amdgcn_rcpf(x);
#else
  return 1.0f / x;
#endif
}

// LDS-only barrier: don't drain vmcnt (ys stores / gi prefetch keep flowing)
#define BARL() asm volatile("s_waitcnt lgkmcnt(0)\n\ts_barrier" ::: "memory")

// swizzled byte offset of element (row, colf16) in a [16][128] f16 tile
__device__ __forceinline__ int swz_off(int row, int colf16) {
  return row * 256 + ((colf16 * 2) ^ ((row & 7) << 4));
}

__device__ __forceinline__ void store4f16(_Float16* base, int row, int colf16,
                                          float4 v) {
  union { f16x4 h; unsigned long long u; } p;
  p.h[0] = (_Float16)v.x; p.h[1] = (_Float16)v.y;
  p.h[2] = (_Float16)v.z; p.h[3] = (_Float16)v.w;
  *(unsigned long long*)((char*)base + swz_off(row, colf16)) = p.u;
}

// ---------------- phase 1: gi[(t*B+b)*384] (f16) = seq @ Wi ----------------
__global__ __launch_bounds__(256, 2)
void gi_gemm(const float* __restrict__ seq, const float* __restrict__ Wi,
             _Float16* __restrict__ gi) {
  const int tid = threadIdx.x;
  const int w = tid >> 6, lane = tid & 63;
  const int q = lane >> 4, s = lane & 15;

  f16x8 wF[6][4];
#pragma unroll
  for (int j = 0; j < 6; j++) {
    const int col = w * 96 + j * 16 + s;
#pragma unroll
    for (int kk = 0; kk < 4; kk++) {
      f16x8 f;
#pragma unroll
      for (int e = 0; e < 8; e++)
        f[e] = (_Float16)Wi[(size_t)(kk * 32 + q * 8 + e) * 384 + col];
      wF[j][kk] = f;
    }
  }

  __shared__ __align__(16) _Float16 gis[16 * 384];
  const int NROWTILES = (T_STEPS * B_SZ) / 16;

  for (int r = blockIdx.x; r < NROWTILES; r += gridDim.x) {
    const float* xr = &seq[((size_t)r * 16 + s) * D_SZ];
    f16x8 af[4];
#pragma unroll
    for (int kk = 0; kk < 4; kk++) {
      float4 u0 = *(const float4*)(xr + kk * 32 + q * 8);
      float4 u1 = *(const float4*)(xr + kk * 32 + q * 8 + 4);
      f16x8 f;
      f[0] = (_Float16)u0.x; f[1] = (_Float16)u0.y;
      f[2] = (_Float16)u0.z; f[3] = (_Float16)u0.w;
      f[4] = (_Float16)u1.x; f[5] = (_Float16)u1.y;
      f[6] = (_Float16)u1.z; f[7] = (_Float16)u1.w;
      af[kk] = f;
    }
    f32x4 acc[6];
#pragma unroll
    for (int j = 0; j < 6; j++) acc[j] = (f32x4){0.f, 0.f, 0.f, 0.f};
#pragma unroll
    for (int kk = 0; kk < 4; kk++)
#pragma unroll
      for (int j = 0; j < 6; j++)
        acc[j] = __builtin_amdgcn_mfma_f32_16x16x32_f16(af[kk], wF[j][kk],
                                                        acc[j], 0, 0, 0);
#pragma unroll
    for (int j = 0; j < 6; j++) {
      const int col = w * 96 + j * 16 + s;
#pragma unroll
      for (int e = 0; e < 4; e++)
        gis[(q * 4 + e) * 384 + col] = (_Float16)acc[j][e];
    }
    __syncthreads();
    const size_t base = (size_t)r * 16 * 384;
#pragma unroll
    for (int i = 0; i < 3; i++) {
      const int idx = tid + i * 256;
      *(float4*)(gi + base + (size_t)idx * 8) = *(const float4*)(gis + idx * 8);
    }
    __syncthreads();
  }
}

// ---------------- phase 2: 16-batch MFMA scan ------------------------------
struct GiRegs {
  _Float16 rz[2][2][4];  // [gate r/z][cg][row j]
  _Float16 nn[2][4];     // [cg][row j]
};

#define GILOADF(T_, G_) { \
    int tl_ = (T_); if (tl_ > T_STEPS - 1) tl_ = T_STEPS - 1; \
    const _Float16* base_ = gi + ((size_t)tl_ * B_SZ + bb) * 384; \
    _Pragma("unroll") for (int gg_ = 0; gg_ < 2; gg_++) \
    _Pragma("unroll") for (int cg_ = 0; cg_ < 2; cg_++) \
    _Pragma("unroll") for (int j_ = 0; j_ < 4; j_++) \
      G_.rz[gg_][cg_][j_] = base_[(size_t)(q * 4 + j_) * 384 + gg_ * H_SZ + \
                                  w * 32 + cg_ * 16 + s]; \
    _Pragma("unroll") for (int cg_ = 0; cg_ < 2; cg_++) \
    _Pragma("unroll") for (int j_ = 0; j_ < 4; j_++) \
      G_.nn[cg_][j_] = base_[(size_t)(q * 4 + j_) * 384 + 2 * H_SZ + \
                             w * 32 + cg_ * 16 + s]; }

#define STEP4(T_, G_) { \
    const int p_ = (T_) & 1; \
    /* A-frags: row s, k = kk*32 + q*8 .. +8 */ \
    f16x8 hf_[4]; \
    _Pragma("unroll") for (int kk_ = 0; kk_ < 4; kk_++) \
      hf_[kk_] = *(const f16x8*)((const char*)ht[p_] + \
                                 swz_off(s, kk_ * 32 + q * 8)); \
    /* consume G_ into acc inits BEFORE refilling it */ \
    f32x4 aR_[2], aZ_[2], aN_[2]; \
    float gn_[2][4]; \
    _Pragma("unroll") for (int cg_ = 0; cg_ < 2; cg_++) { \
      _Pragma("unroll") for (int j_ = 0; j_ < 4; j_++) { \
        aR_[cg_][j_] = (float)G_.rz[0][cg_][j_]; \
        aZ_[cg_][j_] = (float)G_.rz[1][cg_][j_]; \
        aN_[cg_][j_] = 0.f; \
        gn_[cg_][j_] = (float)G_.nn[cg_][j_]; } } \
    GILOADF((T_) + 2, G_) \
    _Pragma("unroll") for (int kk_ = 0; kk_ < 4; kk_++) { \
      aR_[0] = __builtin_amdgcn_mfma_f32_16x16x32_f16(hf_[kk_], whF[0][0][kk_], aR_[0], 0, 0, 0); \
      aZ_[0] = __builtin_amdgcn_mfma_f32_16x16x32_f16(hf_[kk_], whF[1][0][kk_], aZ_[0], 0, 0, 0); \
      aN_[0] = __builtin_amdgcn_mfma_f32_16x16x32_f16(hf_[kk_], whF[2][0][kk_], aN_[0], 0, 0, 0); \
      aR_[1] = __builtin_amdgcn_mfma_f32_16x16x32_f16(hf_[kk_], whF[0][1][kk_], aR_[1], 0, 0, 0); \
      aZ_[1] = __builtin_amdgcn_mfma_f32_16x16x32_f16(hf_[kk_], whF[1][1][kk_], aZ_[1], 0, 0, 0); \
      aN_[1] = __builtin_amdgcn_mfma_f32_16x16x32_f16(hf_[kk_], whF[2][1][kk_], aN_[1], 0, 0, 0); } \
    const unsigned rn_ = rstm[((T_) + 1) & (T_STEPS - 1)]; \
    _Float16* hwp_ = ht[p_ ^ 1]; \
    _Pragma("unroll") for (int cg_ = 0; cg_ < 2; cg_++) { \
      const int ch_ = w * 32 + cg_ * 16 + s; \
      _Pragma("unroll") for (int j_ = 0; j_ < 4; j_++) { \
        const int row_ = q * 4 + j_; \
        const float ar_ = aR_[cg_][j_] + bhv[0][cg_]; \
        const float az_ = aZ_[cg_][j_] + bhv[1][cg_]; \
        const float an_ = aN_[cg_][j_] + bhv[2][cg_]; \
        const float r_ = fastrcp(1.f + __expf(-ar_)); \
        const float z_ = fastrcp(1.f + __expf(-az_)); \
        const float ta_ = gn_[cg_][j_] + r_ * an_; \
        const float e2_ = __expf(2.f * ta_); \
        const float n_ = 1.f - 2.f * fastrcp(e2_ + 1.f); \
        const float hnew_ = n_ + z_ * (hu[cg_][j_] - n_); \
        ys[((size_t)(T_) * B_SZ + bb + row_) * H_SZ + ch_] = hnew_; \
        if ((T_) == T_STEPS - 1) out[(size_t)(bb + row_) * H_SZ + ch_] = hnew_; \
        const float he_ = ((rn_ >> row_) & 1u) ? h0r[cg_][j_] : hnew_; \
        hu[cg_][j_] = he_; \
        *(_Float16*)((char*)hwp_ + swz_off(row_, ch_)) = (_Float16)he_; } } \
    BARL(); }

__global__ __launch_bounds__(NSCAN_THR, 1)
void gru_scan4(const _Float16* __restrict__ gi,
               const int* __restrict__ resets,
               const float* __restrict__ h0,
               const float* __restrict__ Wh,
               const float* __restrict__ bh,
               float* __restrict__ out) {
  const int bb = blockIdx.x * BPB;
  const int tid = threadIdx.x;
  const int w = tid >> 6;          // wave 0..3: hidden cols [w*32, w*32+32)
  const int lane = tid & 63;
  const int q = lane >> 4;         // A k-group / C row-group
  const int s = lane & 15;         // A row (batch) / B,C col

  __shared__ unsigned rstm[T_STEPS];                    // 4 KB bitmasks
  __shared__ __align__(16) _Float16 ht[2][BPB * H_SZ];  // 8 KB, swizzled

  // reset bitmasks: bit j = resets[t][bb+j]
  for (int i = 0; i < 4; i++) {
    const int tt = i * NSCAN_THR + tid;
    const int* rp = &resets[(size_t)tt * B_SZ + bb];
    unsigned m = 0;
#pragma unroll
    for (int j = 0; j < BPB; j++) m |= (rp[j] != 0 ? 1u : 0u) << j;
    rstm[tt] = m;
  }

  // Wh B-frags: gate g, colgroup cg -> col g*128 + w*32 + cg*16 + s
  f16x8 whF[3][2][4];
#pragma unroll
  for (int g3 = 0; g3 < 3; g3++)
#pragma unroll
    for (int cg = 0; cg < 2; cg++) {
      const int col = g3 * H_SZ + w * 32 + cg * 16 + s;
#pragma unroll
      for (int kk = 0; kk < 4; kk++) {
        f16x8 f;
#pragma unroll
        for (int e = 0; e < 8; e++)
          f[e] = (_Float16)Wh[(size_t)(kk * 32 + q * 8 + e) * 384 + col];
        whF[g3][cg][kk] = f;
      }
    }

  float h0r[2][4], hu[2][4], bhv[3][2];
#pragma unroll
  for (int cg = 0; cg < 2; cg++) {
    const int ch = w * 32 + cg * 16 + s;
    bhv[0][cg] = bh[ch];
    bhv[1][cg] = bh[H_SZ + ch];
    bhv[2][cg] = bh[2 * H_SZ + ch];
#pragma unroll
    for (int j = 0; j < 4; j++) {
      const float v = h0[(size_t)(bb + q * 4 + j) * H_SZ + ch];
      h0r[cg][j] = v;
      hu[cg][j] = v;   // reset at t=0 maps h0 -> h0: no-op
    }
  }

  // stage ht[0] = h0 tile (2048 f16 / 256 thr = 8 each)
  {
    const int e0 = tid * 8;
    const int row = e0 >> 7, col0 = e0 & 127;
    float4 a = *(const float4*)&h0[(size_t)(bb + row) * H_SZ + col0];
    float4 b = *(const float4*)&h0[(size_t)(bb + row) * H_SZ + col0 + 4];
    store4f16(ht[0], row, col0, a);
    store4f16(ht[0], row, col0 + 4, b);
  }

  GiRegs giA, giB;
  GILOADF(0, giA)
  GILOADF(1, giB)
  __syncthreads();

  float* ys = out + (size_t)B_SZ * H_SZ;  // out = [final_carry] ++ [ys]

#pragma unroll 1
  for (int t = 0; t < T_STEPS; t += 2) {
    STEP4(t, giA)
    STEP4(t + 1, giB)
  }
}

// ---------------- fallback: fused single-kernel (ws too small) ------------
__global__ __launch_bounds__(512, 2)
void gru_scan_fb(const float* __restrict__ seq,
                 const int* __restrict__ resets,
                 const float* __restrict__ h0,
                 const float* __restrict__ Wi,
                 const float* __restrict__ Wh,
                 const float* __restrict__ bh,
                 float* __restrict__ out) {
  const int b = blockIdx.x;
  const int tid = threadIdx.x;
  const int w = tid >> 6;
  const int lane = tid & 63;
  const int c = (w << 4) | (lane & 15);
  const int g = lane >> 4;

  __shared__ int rst[T_STEPS];
  __shared__ __align__(16) _Float16 x16[2][D_SZ];
  __shared__ __align__(16) _Float16 hh16[2][H_SZ];

  for (int i = tid; i < T_STEPS; i += 512) rst[i] = resets[(size_t)i * B_SZ + b];

  h2 wiR[3][16], whR[3][16];
  const int k0 = g * 32;
#pragma unroll
  for (int ch = 0; ch < 3; ch++) {
    const int col = ch * H_SZ + c;
#pragma unroll
    for (int j = 0; j < 16; j++) {
      const int k = k0 + 2 * j;
      h2 wa; wa.x = (_Float16)Wi[(size_t)k * 384 + col];
             wa.y = (_Float16)Wi[(size_t)(k + 1) * 384 + col];
      wiR[ch][j] = wa;
      h2 wb; wb.x = (_Float16)Wh[(size_t)k * 384 + col];
             wb.y = (_Float16)Wh[(size_t)(k + 1) * 384 + col];
      whR[ch][j] = wb;
    }
  }

  const float bhr = bh[c], bhz = bh[H_SZ + c], bhn = bh[2 * H_SZ + c];
  const float h0c = h0[(size_t)b * H_SZ + c];
  float hu = h0c;

  if (tid < H_SZ) {
    hh16[0][tid] = (_Float16)h0[(size_t)b * H_SZ + tid];
    x16[0][tid]  = (_Float16)seq[((size_t)0 * B_SZ + b) * D_SZ + tid];
  }
  float xA = 0.f, xB = 0.f;
  if (tid < D_SZ) {
    xA = seq[((size_t)1 * B_SZ + b) * D_SZ + tid];
    xB = seq[((size_t)2 * B_SZ + b) * D_SZ + tid];
  }
  __syncthreads();

  float* ys = out + (size_t)B_SZ * H_SZ;

#pragma unroll 1
  for (int t = 0; t < T_STEPS; t++) {
    const int p = t & 1;
    const int rnext = rst[(t + 1) & (T_STEPS - 1)];

    const h8* xb = (const h8*)&x16[p][g * 32];
    const h8* hb = (const h8*)&hh16[p][g * 32];
    float cr = 0.f, cz = 0.f, ci = 0.f, chn = 0.f;
#pragma unroll
    for (int qq = 0; qq < 4; qq++) {
      U8 ux, uh; ux.v = xb[qq]; uh.v = hb[qq];
#pragma unroll
      for (int j = 0; j < 4; j++) {
        const int idx = qq * 4 + j;
        cr  = dot2f(ux.p[j], wiR[0][idx], cr);
        cz  = dot2f(ux.p[j], wiR[1][idx], cz);
        ci  = dot2f(ux.p[j], wiR[2][idx], ci);
        cr  = dot2f(uh.p[j], whR[0][idx], cr);
        cz  = dot2f(uh.p[j], whR[1][idx], cz);
        chn = dot2f(uh.p[j], whR[2][idx], chn);
      }
    }
    cr  += __shfl_xor(cr, 16, 64);
    cz  += __shfl_xor(cz, 16, 64);
    ci  += __shfl_xor(ci, 16, 64);
    chn += __shfl_xor(chn, 16, 64);
    cr  += __shfl_xor(cr, 32, 64);
    cz  += __shfl_xor(cz, 32, 64);
    ci  += __shfl_xor(ci, 32, 64);
    chn += __shfl_xor(chn, 32, 64);

    const float ar = cr + bhr;
    const float az = cz + bhz;
    const float ah = chn + bhn;
    const float r = fastrcp(1.f + __expf(-ar));
    const float z = fastrcp(1.f + __expf(-az));
    const float ta = ci + r * ah;
    const float e2 = __expf(2.f * ta);
    const float n = 1.f - 2.f * fastrcp(e2 + 1.f);
    const float hnew = n + z * (hu - n);
    const float hunew = rnext ? h0c : hnew;
    hu = hunew;

    if (g == 0) {
      ys[((size_t)t * B_SZ + b) * H_SZ + c] = hnew;
      hh16[p ^ 1][c] = (_Float16)hunew;
      if (t == T_STEPS - 1) out[(size_t)b * H_SZ + c] = hnew;
    }
    if (tid < D_SZ) {
      x16[p ^ 1][tid] = (_Float16)xA;
      xA = xB;
      int tt = t + 3; if (tt > T_STEPS - 1) tt = T_STEPS - 1;
      xB = seq[((size_t)tt * B_SZ + b) * D_SZ + tid];
    }
    __syncthreads();
  }
}

extern "C" void kernel_launch(void* const* d_in, const int* in_sizes, int n_in,
                              void* d_out, int out_size, void* d_ws, size_t ws_size,
                              hipStream_t stream) {
  const float* seq    = (const float*)d_in[0];
  const int*   resets = (const int*)d_in[1];
  const float* h0     = (const float*)d_in[2];
  const float* Wi     = (const float*)d_in[3];
  const float* Wh     = (const float*)d_in[4];
  const float* bh     = (const float*)d_in[5];
  (void)in_sizes; (void)n_in; (void)out_size;

  const size_t need = (size_t)T_STEPS * B_SZ * 384 * sizeof(_Float16);
  if (ws_size >= need && d_ws != nullptr) {
    _Float16* gi = (_Float16*)d_ws;
    gi_gemm<<<1024, 256, 0, stream>>>(seq, Wi, gi);
    gru_scan4<<<B_SZ / BPB, NSCAN_THR, 0, stream>>>(gi, resets, h0, Wh, bh,
                                                    (float*)d_out);
  } else {
    gru_scan_fb<<<B_SZ, 512, 0, stream>>>(seq, resets, h0, Wi, Wh, bh,
                                          (float*)d_out);
  }
}

// Round 8
// 618.598 us; speedup vs baseline: 2.1238x; 2.1238x over previous
//
#include <hip/hip_runtime.h>
#include <hip/hip_bf16.h>

// GRU scan with sparse resets. T=1024, B=256, D=128, H=128.
// Round 8: Phase 1: gi = seq @ Wi (f16 -> d_ws, pre-scaled by 1/ln2 (r,z)
// and 2/ln2 (n) so gates use raw v_exp_f32=2^x). Phase 2: BPB=1 MFMA scan:
// 256 blocks x 256 thr (4 waves). h replicated across all 16 A-rows ->
// mfma_16x16x32_f16 does the k-reduction internally: NO shuffle reduce.
// Per wave: 2 col-tiles x 3 gates x 4 k-chunks = 24 MFMA; each lane owns
// cols {w*32+s, w*32+16+s} with full sums in C row 0. h tile = 256 B linear
// LDS (broadcast reads). Lane roles by q: q0 -> h writeback, q1 -> ys
// store, q2 -> final carry. BARL (lgkmcnt-only) barrier; gi prefetched
// 4 steps (1 base addr + immediate offsets). Fallback if ws too small.

#define T_STEPS 1024
#define B_SZ 256
#define D_SZ 128
#define H_SZ 128

#define SC_RZ 1.44269504f   // 1/ln2
#define SC_N  2.88539008f   // 2/ln2

typedef _Float16 h2 __attribute__((ext_vector_type(2)));
typedef _Float16 h8 __attribute__((ext_vector_type(8)));
typedef _Float16 f16x8 __attribute__((ext_vector_type(8)));
typedef float f32x4 __attribute__((ext_vector_type(4)));

union U8 { h8 v; h2 p[4]; };

__device__ __forceinline__ float dot2f(h2 a, h2 b, float c) {
#if __has_builtin(__builtin_amdgcn_fdot2)
  return __builtin_amdgcn_fdot2(a, b, c, false);
#else
  return c + (float)a.x * (float)b.x + (float)a.y * (float)b.y;
#endif
}

__device__ __forceinline__ float fastrcp(float x) {
#if __has_builtin(__builtin_amdgcn_rcpf)
  return __builtin_amdgcn_rcpf(x);
#else
  return 1.0f / x;
#endif
}

__device__ __forceinline__ float fexp2(float x) {
#if __has_builtin(__builtin_amdgcn_exp2f)
  return __builtin_amdgcn_exp2f(x);
#else
  return __builtin_exp2f(x);
#endif
}

// LDS-only barrier: don't drain vmcnt (ys stores / gi prefetch keep flowing)
#define BARL() asm volatile("s_waitcnt lgkmcnt(0)\n\ts_barrier" ::: "memory")

// ---------------- phase 1: gi[(t*B+b)*384] (f16, pre-scaled) = seq @ Wi ----
__global__ __launch_bounds__(256, 2)
void gi_gemm(const float* __restrict__ seq, const float* __restrict__ Wi,
             _Float16* __restrict__ gi) {
  const int tid = threadIdx.x;
  const int w = tid >> 6, lane = tid & 63;
  const int q = lane >> 4, s = lane & 15;

  f16x8 wF[6][4];
#pragma unroll
  for (int j = 0; j < 6; j++) {
    const int col = w * 96 + j * 16 + s;
    const float sc = (w * 96 + j * 16) >= 256 ? SC_N : SC_RZ;  // gate of col
#pragma unroll
    for (int kk = 0; kk < 4; kk++) {
      f16x8 f;
#pragma unroll
      for (int e = 0; e < 8; e++)
        f[e] = (_Float16)(sc * Wi[(size_t)(kk * 32 + q * 8 + e) * 384 + col]);
      wF[j][kk] = f;
    }
  }

  __shared__ __align__(16) _Float16 gis[16 * 384];
  const int NROWTILES = (T_STEPS * B_SZ) / 16;

  for (int r = blockIdx.x; r < NROWTILES; r += gridDim.x) {
    const float* xr = &seq[((size_t)r * 16 + s) * D_SZ];
    f16x8 af[4];
#pragma unroll
    for (int kk = 0; kk < 4; kk++) {
      float4 u0 = *(const float4*)(xr + kk * 32 + q * 8);
      float4 u1 = *(const float4*)(xr + kk * 32 + q * 8 + 4);
      f16x8 f;
      f[0] = (_Float16)u0.x; f[1] = (_Float16)u0.y;
      f[2] = (_Float16)u0.z; f[3] = (_Float16)u0.w;
      f[4] = (_Float16)u1.x; f[5] = (_Float16)u1.y;
      f[6] = (_Float16)u1.z; f[7] = (_Float16)u1.w;
      af[kk] = f;
    }
    f32x4 acc[6];
#pragma unroll
    for (int j = 0; j < 6; j++) acc[j] = (f32x4){0.f, 0.f, 0.f, 0.f};
#pragma unroll
    for (int kk = 0; kk < 4; kk++)
#pragma unroll
      for (int j = 0; j < 6; j++)
        acc[j] = __builtin_amdgcn_mfma_f32_16x16x32_f16(af[kk], wF[j][kk],
                                                        acc[j], 0, 0, 0);
#pragma unroll
    for (int j = 0; j < 6; j++) {
      const int col = w * 96 + j * 16 + s;
#pragma unroll
      for (int e = 0; e < 4; e++)
        gis[(q * 4 + e) * 384 + col] = (_Float16)acc[j][e];
    }
    __syncthreads();
    const size_t base = (size_t)r * 16 * 384;
#pragma unroll
    for (int i = 0; i < 3; i++) {
      const int idx = tid + i * 256;
      *(float4*)(gi + base + (size_t)idx * 8) = *(const float4*)(gis + idx * 8);
    }
    __syncthreads();
  }
}

// ---------------- phase 2: BPB=1 MFMA scan ---------------------------------
struct Gi5 { _Float16 v[6]; };  // {r0,r1,z0,z1,n0,n1} for cols c0, c0+16

#define GIL5(T_, G_) { \
    int tl_ = (T_); if (tl_ > T_STEPS - 1) tl_ = T_STEPS - 1; \
    const _Float16* gp_ = gi + ((size_t)tl_ * B_SZ + b) * 384 + c0; \
    G_.v[0] = gp_[0];   G_.v[1] = gp_[16]; \
    G_.v[2] = gp_[128]; G_.v[3] = gp_[144]; \
    G_.v[4] = gp_[256]; G_.v[5] = gp_[272]; }

#define STEP5(T_, G_) { \
    const int p_ = (T_) & 1; \
    const int rn_ = rst[((T_) + 1) & (T_STEPS - 1)]; \
    f16x8 hf_[4]; \
    _Pragma("unroll") for (int kk_ = 0; kk_ < 4; kk_++) \
      hf_[kk_] = *(const f16x8*)&ht[p_][kk_ * 32 + q * 8]; \
    const float gr0_ = (float)G_.v[0], gr1_ = (float)G_.v[1]; \
    const float gz0_ = (float)G_.v[2], gz1_ = (float)G_.v[3]; \
    const float gn0_ = (float)G_.v[4], gn1_ = (float)G_.v[5]; \
    GIL5((T_) + 4, G_) \
    f32x4 aR0_ = {gr0_, 0.f, 0.f, 0.f}, aR1_ = {gr1_, 0.f, 0.f, 0.f}; \
    f32x4 aZ0_ = {gz0_, 0.f, 0.f, 0.f}, aZ1_ = {gz1_, 0.f, 0.f, 0.f}; \
    f32x4 aN0_ = {0.f, 0.f, 0.f, 0.f},  aN1_ = {0.f, 0.f, 0.f, 0.f}; \
    _Pragma("unroll") for (int kk_ = 0; kk_ < 4; kk_++) { \
      aR0_ = __builtin_amdgcn_mfma_f32_16x16x32_f16(hf_[kk_], whF[0][0][kk_], aR0_, 0, 0, 0); \
      aZ0_ = __builtin_amdgcn_mfma_f32_16x16x32_f16(hf_[kk_], whF[1][0][kk_], aZ0_, 0, 0, 0); \
      aN0_ = __builtin_amdgcn_mfma_f32_16x16x32_f16(hf_[kk_], whF[2][0][kk_], aN0_, 0, 0, 0); \
      aR1_ = __builtin_amdgcn_mfma_f32_16x16x32_f16(hf_[kk_], whF[0][1][kk_], aR1_, 0, 0, 0); \
      aZ1_ = __builtin_amdgcn_mfma_f32_16x16x32_f16(hf_[kk_], whF[1][1][kk_], aZ1_, 0, 0, 0); \
      aN1_ = __builtin_amdgcn_mfma_f32_16x16x32_f16(hf_[kk_], whF[2][1][kk_], aN1_, 0, 0, 0); } \
    const float r0_ = fastrcp(1.f + fexp2(-(aR0_[0] + bh_r0))); \
    const float z0_ = fastrcp(1.f + fexp2(-(aZ0_[0] + bh_z0))); \
    const float e20_ = fexp2(gn0_ + r0_ * (aN0_[0] + bh_n0)); \
    const float n0_ = 1.f - 2.f * fastrcp(e20_ + 1.f); \
    const float h0n_ = n0_ + z0_ * (hu0 - n0_); \
    const float r1_ = fastrcp(1.f + fexp2(-(aR1_[0] + bh_r1))); \
    const float z1_ = fastrcp(1.f + fexp2(-(aZ1_[0] + bh_z1))); \
    const float e21_ = fexp2(gn1_ + r1_ * (aN1_[0] + bh_n1)); \
    const float n1_ = 1.f - 2.f * fastrcp(e21_ + 1.f); \
    const float h1n_ = n1_ + z1_ * (hu1 - n1_); \
    hu0 = rn_ ? h0c0 : h0n_; \
    hu1 = rn_ ? h0c1 : h1n_; \
    if (q == 0) { \
      ht[p_ ^ 1][c0] = (_Float16)hu0; \
      ht[p_ ^ 1][c0 + 16] = (_Float16)hu1; \
    } else if (q == 1) { \
      float* yp_ = &ys[((size_t)(T_) * B_SZ + b) * H_SZ + c0]; \
      yp_[0] = h0n_; yp_[16] = h1n_; \
    } else if (q == 2 && (T_) == T_STEPS - 1) { \
      out[(size_t)b * H_SZ + c0] = h0n_; \
      out[(size_t)b * H_SZ + c0 + 16] = h1n_; \
    } \
    BARL(); }

__global__ __launch_bounds__(256, 1)
void gru_scan5(const _Float16* __restrict__ gi,
               const int* __restrict__ resets,
               const float* __restrict__ h0,
               const float* __restrict__ Wh,
               const float* __restrict__ bh,
               float* __restrict__ out) {
  const int b = blockIdx.x;
  const int tid = threadIdx.x;
  const int w = tid >> 6;          // wave 0..3: cols [w*32, w*32+32)
  const int lane = tid & 63;
  const int q = lane >> 4;         // A k-group / role group
  const int s = lane & 15;         // B/C col within tile
  const int c0 = w * 32 + s;       // first owned column (second = c0+16)

  __shared__ int rst[T_STEPS];                      // 4 KB
  __shared__ __align__(16) _Float16 ht[2][H_SZ];    // 512 B, linear

  for (int i = tid; i < T_STEPS; i += 256)
    rst[i] = resets[(size_t)i * B_SZ + b];

  // Wh B-frags (pre-scaled): gate g3, colgroup cg -> col g3*128 + w*32 +
  // cg*16 + s; k = kk*32 + q*8 + e.
  f16x8 whF[3][2][4];
#pragma unroll
  for (int g3 = 0; g3 < 3; g3++) {
    const float sc = (g3 == 2) ? SC_N : SC_RZ;
#pragma unroll
    for (int cg = 0; cg < 2; cg++) {
      const int col = g3 * H_SZ + w * 32 + cg * 16 + s;
#pragma unroll
      for (int kk = 0; kk < 4; kk++) {
        f16x8 f;
#pragma unroll
        for (int e = 0; e < 8; e++)
          f[e] = (_Float16)(sc * Wh[(size_t)(kk * 32 + q * 8 + e) * 384 + col]);
        whF[g3][cg][kk] = f;
      }
    }
  }

  const float bh_r0 = SC_RZ * bh[c0],           bh_r1 = SC_RZ * bh[c0 + 16];
  const float bh_z0 = SC_RZ * bh[H_SZ + c0],    bh_z1 = SC_RZ * bh[H_SZ + c0 + 16];
  const float bh_n0 = SC_N  * bh[2 * H_SZ + c0], bh_n1 = SC_N * bh[2 * H_SZ + c0 + 16];

  const float h0c0 = h0[(size_t)b * H_SZ + c0];
  const float h0c1 = h0[(size_t)b * H_SZ + c0 + 16];
  float hu0 = h0c0, hu1 = h0c1;

  if (tid < H_SZ) ht[0][tid] = (_Float16)h0[(size_t)b * H_SZ + tid];

  Gi5 gA, gB, gC, gD;
  GIL5(0, gA)
  GIL5(1, gB)
  GIL5(2, gC)
  GIL5(3, gD)
  __syncthreads();

  float* ys = out + (size_t)B_SZ * H_SZ;  // out = [final_carry] ++ [ys]

#pragma unroll 1
  for (int t = 0; t < T_STEPS; t += 8) {
    STEP5(t + 0, gA)
    STEP5(t + 1, gB)
    STEP5(t + 2, gC)
    STEP5(t + 3, gD)
    STEP5(t + 4, gA)
    STEP5(t + 5, gB)
    STEP5(t + 6, gC)
    STEP5(t + 7, gD)
  }
}

// ---------------- fallback: fused single-kernel (ws too small) ------------
__global__ __launch_bounds__(512, 2)
void gru_scan_fb(const float* __restrict__ seq,
                 const int* __restrict__ resets,
                 const float* __restrict__ h0,
                 const float* __restrict__ Wi,
                 const float* __restrict__ Wh,
                 const float* __restrict__ bh,
                 float* __restrict__ out) {
  const int b = blockIdx.x;
  const int tid = threadIdx.x;
  const int w = tid >> 6;
  const int lane = tid & 63;
  const int c = (w << 4) | (lane & 15);
  const int g = lane >> 4;

  __shared__ int rst[T_STEPS];
  __shared__ __align__(16) _Float16 x16[2][D_SZ];
  __shared__ __align__(16) _Float16 hh16[2][H_SZ];

  for (int i = tid; i < T_STEPS; i += 512) rst[i] = resets[(size_t)i * B_SZ + b];

  h2 wiR[3][16], whR[3][16];
  const int k0 = g * 32;
#pragma unroll
  for (int ch = 0; ch < 3; ch++) {
    const int col = ch * H_SZ + c;
#pragma unroll
    for (int j = 0; j < 16; j++) {
      const int k = k0 + 2 * j;
      h2 wa; wa.x = (_Float16)Wi[(size_t)k * 384 + col];
             wa.y = (_Float16)Wi[(size_t)(k + 1) * 384 + col];
      wiR[ch][j] = wa;
      h2 wb; wb.x = (_Float16)Wh[(size_t)k * 384 + col];
             wb.y = (_Float16)Wh[(size_t)(k + 1) * 384 + col];
      whR[ch][j] = wb;
    }
  }

  const float bhr = bh[c], bhz = bh[H_SZ + c], bhn = bh[2 * H_SZ + c];
  const float h0c = h0[(size_t)b * H_SZ + c];
  float hu = h0c;

  if (tid < H_SZ) {
    hh16[0][tid] = (_Float16)h0[(size_t)b * H_SZ + tid];
    x16[0][tid]  = (_Float16)seq[((size_t)0 * B_SZ + b) * D_SZ + tid];
  }
  float xA = 0.f, xB = 0.f;
  if (tid < D_SZ) {
    xA = seq[((size_t)1 * B_SZ + b) * D_SZ + tid];
    xB = seq[((size_t)2 * B_SZ + b) * D_SZ + tid];
  }
  __syncthreads();

  float* ys = out + (size_t)B_SZ * H_SZ;

#pragma unroll 1
  for (int t = 0; t < T_STEPS; t++) {
    const int p = t & 1;
    const int rnext = rst[(t + 1) & (T_STEPS - 1)];

    const h8* xb = (const h8*)&x16[p][g * 32];
    const h8* hb = (const h8*)&hh16[p][g * 32];
    float cr = 0.f, cz = 0.f, ci = 0.f, chn = 0.f;
#pragma unroll
    for (int qq = 0; qq < 4; qq++) {
      U8 ux, uh; ux.v = xb[qq]; uh.v = hb[qq];
#pragma unroll
      for (int j = 0; j < 4; j++) {
        const int idx = qq * 4 + j;
        cr  = dot2f(ux.p[j], wiR[0][idx], cr);
        cz  = dot2f(ux.p[j], wiR[1][idx], cz);
        ci  = dot2f(ux.p[j], wiR[2][idx], ci);
        cr  = dot2f(uh.p[j], whR[0][idx], cr);
        cz  = dot2f(uh.p[j], whR[1][idx], cz);
        chn = dot2f(uh.p[j], whR[2][idx], chn);
      }
    }
    cr  += __shfl_xor(cr, 16, 64);
    cz  += __shfl_xor(cz, 16, 64);
    ci  += __shfl_xor(ci, 16, 64);
    chn += __shfl_xor(chn, 16, 64);
    cr  += __shfl_xor(cr, 32, 64);
    cz  += __shfl_xor(cz, 32, 64);
    ci  += __shfl_xor(ci, 32, 64);
    chn += __shfl_xor(chn, 32, 64);

    const float ar = cr + bhr;
    const float az = cz + bhz;
    const float ah = chn + bhn;
    const float r = fastrcp(1.f + __expf(-ar));
    const float z = fastrcp(1.f + __expf(-az));
    const float ta = ci + r * ah;
    const float e2 = __expf(2.f * ta);
    const float n = 1.f - 2.f * fastrcp(e2 + 1.f);
    const float hnew = n + z * (hu - n);
    const float hunew = rnext ? h0c : hnew;
    hu = hunew;

    if (g == 0) {
      ys[((size_t)t * B_SZ + b) * H_SZ + c] = hnew;
      hh16[p ^ 1][c] = (_Float16)hunew;
      if (t == T_STEPS - 1) out[(size_t)b * H_SZ + c] = hnew;
    }
    if (tid < D_SZ) {
      x16[p ^ 1][tid] = (_Float16)xA;
      xA = xB;
      int tt = t + 3; if (tt > T_STEPS - 1) tt = T_STEPS - 1;
      xB = seq[((size_t)tt * B_SZ + b) * D_SZ + tid];
    }
    __syncthreads();
  }
}

extern "C" void kernel_launch(void* const* d_in, const int* in_sizes, int n_in,
                              void* d_out, int out_size, void* d_ws, size_t ws_size,
                              hipStream_t stream) {
  const float* seq    = (const float*)d_in[0];
  const int*   resets = (const int*)d_in[1];
  const float* h0     = (const float*)d_in[2];
  const float* Wi     = (const float*)d_in[3];
  const float* Wh     = (const float*)d_in[4];
  const float* bh     = (const float*)d_in[5];
  (void)in_sizes; (void)n_in; (void)out_size;

  const size_t need = (size_t)T_STEPS * B_SZ * 384 * sizeof(_Float16);
  if (ws_size >= need && d_ws != nullptr) {
    _Float16* gi = (_Float16*)d_ws;
    gi_gemm<<<1024, 256, 0, stream>>>(seq, Wi, gi);
    gru_scan5<<<B_SZ, 256, 0, stream>>>(gi, resets, h0, Wh, bh, (float*)d_out);
  } else {
    gru_scan_fb<<<B_SZ, 512, 0, stream>>>(seq, resets, h0, Wi, Wh, bh,
                                          (float*)d_out);
  }
}